// Round 14
// baseline (106.981 us; speedup 1.0000x reference)
//
#include <hip/hip_runtime.h>
#include <stdint.h>

#define NN   4096
#define KK   32
#define HID  128
#define BLK  256
#define NPB  2                 // nodes per block
#define GRID (NN / NPB)        // 2048 blocks
#define CAP  128

typedef unsigned short bf16_t;
typedef __attribute__((ext_vector_type(8))) short bf16x8;
typedef __attribute__((ext_vector_type(4))) float f32x4;
typedef __attribute__((ext_vector_type(2))) float f32x2;

#define FINF __uint_as_float(0x7f800000u)

__device__ __forceinline__ uint32_t pk2bf(float lo, float hi) {
    uint32_t r;
    asm("v_cvt_pk_bf16_f32 %0, %1, %2" : "=v"(r) : "v"(lo), "v"(hi));
    return r;
}
__device__ __forceinline__ float fastrcp(float x) {
    float r; asm("v_rcp_f32 %0, %1" : "=v"(r) : "v"(x)); return r;
}
__device__ __forceinline__ float fastrsq(float x) {
    float r; asm("v_rsq_f32 %0, %1" : "=v"(r) : "v"(x)); return r;
}
__device__ __forceinline__ float siluf(float x) {
    return x * fastrcp(1.0f + __expf(-x));
}
__device__ __forceinline__ f32x2 pk_add(f32x2 a, f32x2 b) {
    f32x2 r; asm("v_pk_add_f32 %0, %1, %2" : "=v"(r) : "v"(a), "v"(b)); return r;
}
__device__ __forceinline__ f32x2 pk_sq(f32x2 a) {
    f32x2 r; asm("v_pk_mul_f32 %0, %1, %1" : "=v"(r) : "v"(a)); return r;
}

// DPP cross-lane sums (VALU pipe, no LDS)
template<int CTRL>
__device__ __forceinline__ float rsum_step(float x) {
    return x + __int_as_float(__builtin_amdgcn_update_dpp(
        0, __float_as_int(x), CTRL, 0xF, 0xF, true));
}
__device__ __forceinline__ float rowsum16(float x) {
    x = rsum_step<0xB1>(x);
    x = rsum_step<0x4E>(x);
    x = rsum_step<0x124>(x);
    x = rsum_step<0x128>(x);
    return x;
}
__device__ __forceinline__ float wsum64(float x) {
    x = rowsum16(x);
    x += __shfl_xor(x, 16, 64);
    x += __shfl_xor(x, 32, 64);
    return x;
}

// exact scalar distance (cold fallback only) — reference IEEE chain
__device__ __forceinline__ void dist4s(const float4* __restrict__ p4, int g, int lane,
                                       float px, float py, float pz, float d[4]) {
    float4 f0 = p4[g*192 + 3*lane];
    float4 f1 = p4[g*192 + 3*lane + 1];
    float4 f2 = p4[g*192 + 3*lane + 2];
    float jx[4] = {f0.x, f0.w, f1.z, f2.y};
    float jy[4] = {f0.y, f1.x, f1.w, f2.z};
    float jz[4] = {f0.z, f1.y, f2.x, f2.w};
    #pragma unroll
    for (int c = 0; c < 4; ++c) {
        float dx = px - jx[c], dy = py - jy[c], dz = pz - jz[c];
        d[c] = __fadd_rn(__fadd_rn(__fmul_rn(dx,dx), __fmul_rn(dy,dy)),
                         __fmul_rn(dz,dz));
    }
}

// ---- prepack: W2 fp32 -> bf16 in MFMA B-fragment order (frag f = NT*4+kk) ----
__global__ __launch_bounds__(256) void prepack_w2(
    const float* __restrict__ W2, uint4* __restrict__ w2b)
{
    int c  = blockIdx.x * 256 + threadIdx.x;
    int f  = c >> 6, ln = c & 63;
    int NT = f >> 2, kk = f & 3;
    int row = NT*16 + (ln & 15);
    int k0  = kk*32 + (ln >> 4) * 8;
    const float* s = W2 + row * HID + k0;
    float4 lo = *(const float4*)s;
    float4 hi = *(const float4*)(s + 4);
    uint4 pk;
    pk.x = pk2bf(lo.x, lo.y);
    pk.y = pk2bf(lo.z, lo.w);
    pk.z = pk2bf(hi.x, hi.y);
    pk.w = pk2bf(hi.z, hi.w);
    w2b[c] = pk;
}

template<bool WS>
struct __align__(16) Sm {
    ushort   h1[NPB][KK * HID];         // 16 KB: MFMA A-operand per node
    uint32_t cand[NPB][CAP];            // 1 KB
    uint32_t ccnt[NPB];                 // shared candidate counter per node
    ushort   smin[NPB][2][64];          // per-lane half-mins exchange
    float    sedge[NPB][KK];
    int      recvs[NPB][KK];
    float    partial[NPB][2][4];        // final message partials per wave
    uint32_t w2l[WS ? 4 : HID * 64];    // W2 staging only in no-workspace path
};

template<bool WS>
__global__ __launch_bounds__(BLK) void egnn_main(
    // natural VGPR, 4 waves/SIMD. Constraints learned this session:
    //  - NO min-waves bound: 8 waves/EU caps TOTAL regs at 64 incl. the 32-reg
    //    MFMA accumulator -> 32 arch VGPRs left -> catastrophic spills (R11).
    //  - NO hoisting epilogue constants to entry: +24 regs live across phases
    //    A-E starves phase-A scheduling (R12, +7us; confirmed by R13 revert).
    const float* __restrict__ pos, const float* __restrict__ tptr,
    const float* __restrict__ W1,  const float* __restrict__ b1,
    const float* __restrict__ g1,  const float* __restrict__ W2,
    const float* __restrict__ b2,  const float* __restrict__ g2,
    const float* __restrict__ W3,  const float* __restrict__ b3,
    const uint4* __restrict__ w2b, float* __restrict__ out)
{
    __shared__ Sm<WS> sm;
    const int tid  = threadIdx.x;
    const int lane = tid & 63;
    const int wid  = tid >> 6;                  // 0..3
    const int p    = wid >> 1;                  // node slot in block (0..1)
    const int sub  = wid & 1;                   // half-wave of the pair
    const int i    = blockIdx.x * NPB + p;      // node handled by this pair
    const int l15  = lane & 15, lq = lane >> 4;

    if (tid < NPB) sm.ccnt[tid] = 0;            // visible after B1

    const float ts  = tptr[0];
    const float b3s = b3[0];

    // closed-form RMS coefficients (wave-reduced -> lane-uniform)
    float A2, AC, C2;
    {
        const float4 w1v = ((const float4*)W1)[lane];
        const float2 b1v = ((const float2*)b1)[lane];
        float t0 = ts * w1v.y + b1v.x;
        float t1 = ts * w1v.w + b1v.y;
        A2 = wsum64(w1v.x*w1v.x + w1v.z*w1v.z);
        AC = wsum64(w1v.x*t0    + w1v.z*t1);
        C2 = wsum64(t0*t0       + t1*t1);
    }

    if constexpr (!WS) {
        for (int idx = tid; idx < HID * 16; idx += BLK) {
            int row = idx >> 4, c = idx & 15;
            const float* src = W2 + row * HID + c * 8;
            float4 lo = *(const float4*)src;
            float4 hi = *(const float4*)(src + 4);
            uint4 pk;
            pk.x = pk2bf(lo.x, lo.y);
            pk.y = pk2bf(lo.z, lo.w);
            pk.z = pk2bf(hi.x, hi.y);
            pk.w = pk2bf(hi.z, hi.w);
            *((uint4*)&sm.w2l[row * 64 + 4 * (c ^ (row & 15))]) = pk;
        }
        // made visible by B1 below (before any w2l read)
    }

    const float px = pos[3*i], py = pos[3*i+1], pz = pos[3*i+2];
    const float4* p4 = (const float4*)pos;
    const f32x2 nPxy = {-px, -py}, nPzx = {-pz, -px}, nPyz = {-py, -pz};

    const int  sgrp     = i >> 8;
    const bool selfLane = ((i >> 2) & 63) == lane;
    const int  selfc    = i & 3;

    // ---- phase A: own-half distances (8 of 16 groups) into REGISTERS ----
    uint32_t dlo[8], dhi[8];
    float mind = FINF;
    #pragma unroll
    for (int gg = 0; gg < 8; ++gg) {
        const int g = sub*8 + gg;
        float4 f0 = p4[g*192 + 3*lane];   // x0 y0 z0 x1
        float4 f1 = p4[g*192 + 3*lane+1]; // y1 z1 x2 y2
        float4 f2 = p4[g*192 + 3*lane+2]; // z2 x3 y3 z3
        f32x2 S0 = pk_sq(pk_add(f32x2{f0.x, f0.y}, nPxy));
        f32x2 S1 = pk_sq(pk_add(f32x2{f0.z, f0.w}, nPzx));
        f32x2 S2 = pk_sq(pk_add(f32x2{f1.x, f1.y}, nPyz));
        f32x2 S3 = pk_sq(pk_add(f32x2{f1.z, f1.w}, nPxy));
        f32x2 S4 = pk_sq(pk_add(f32x2{f2.x, f2.y}, nPzx));
        f32x2 S5 = pk_sq(pk_add(f32x2{f2.z, f2.w}, nPyz));
        float d0 = S0.x + S0.y + S1.x;
        float d1 = S1.y + S2.x + S2.y;
        float d2 = S3.x + S3.y + S4.x;
        float d3 = S4.y + S5.x + S5.y;
        if (g == sgrp && selfLane) {
            d0 = (selfc == 0) ? FINF : d0;
            d1 = (selfc == 1) ? FINF : d1;
            d2 = (selfc == 2) ? FINF : d2;
            d3 = (selfc == 3) ? FINF : d3;
        }
        dlo[gg] = __builtin_amdgcn_perm(__float_as_uint(d1),
                                        __float_as_uint(d0), 0x07060302u);
        dhi[gg] = __builtin_amdgcn_perm(__float_as_uint(d3),
                                        __float_as_uint(d2), 0x07060302u);
        mind = fminf(fminf(fminf(mind, d0), fminf(d1, d2)), d3);
    }
    // exchange per-lane half-mins across the pair
    const uint32_t m16own = __float_as_uint(mind) >> 16;
    sm.smin[p][sub][lane] = (ushort)m16own;
    __syncthreads();                                        // B1
    uint32_t m16;
    {
        uint32_t o = (uint32_t)sm.smin[p][sub ^ 1][lane];
        m16 = m16own < o ? m16own : o;                      // full 64-j lane min
    }

    // ---- v = 32nd smallest combined sample-min (radix; duplicated per wave).
    //      Bit 15 skipped: distances >= 0 (self=+inf=0x7f80) => m16 < 0x8000
    //      for every lane => that iteration provably leaves v = 0. ----
    uint32_t v = 0;
    #pragma unroll
    for (int b = 14; b >= 0; --b) {
        uint32_t t = v | (1u << b);
        int nl = (int)__popcll(__ballot(m16 < t));
        if (nl < KK) v = t;
    }

    // ---- phase B: compaction, AGGREGATED atomics: per gg, 4 ballots + ONE
    //      ds_add by lane 0 (+SALU readfirstlane broadcast) + prefix slots.
    //      ~8 serialized same-address LDS atomics/wave instead of ~30 (the
    //      per-candidate atomic chain sat on the B1->B2 critical path).
    //      Same candidate set and cnt; slot order irrelevant (rank by key). ----
    {
        const uint32_t vk = (v << 16) | 0xffffu;
        const unsigned long long below = (1ull << lane) - 1ull;
        #pragma unroll
        for (int gg = 0; gg < 8; ++gg) {
            uint32_t jb = (uint32_t)((sub*8 + gg)*256 + 4*lane);
            uint32_t k0 = (dlo[gg] << 16) | jb;
            uint32_t k1 = (dlo[gg] & 0xffff0000u) | (jb + 1);
            uint32_t k2 = (dhi[gg] << 16) | (jb + 2);
            uint32_t k3 = (dhi[gg] & 0xffff0000u) | (jb + 3);
            bool p0 = k0 <= vk, p1 = k1 <= vk, p2 = k2 <= vk, p3 = k3 <= vk;
            unsigned long long m0 = __ballot(p0), m1 = __ballot(p1);
            unsigned long long m2 = __ballot(p2), m3 = __ballot(p3);
            uint32_t c0   = (uint32_t)__popcll(m0);
            uint32_t c01  = c0  + (uint32_t)__popcll(m1);
            uint32_t c012 = c01 + (uint32_t)__popcll(m2);
            uint32_t tot  = c012 + (uint32_t)__popcll(m3);
            if (tot) {                               // wave-uniform
                uint32_t base = 0;
                if (lane == 0) base = atomicAdd(&sm.ccnt[p], tot);
                base = __builtin_amdgcn_readfirstlane(base);
                uint32_t s0 = base         + (uint32_t)__popcll(m0 & below);
                uint32_t s1 = base + c0    + (uint32_t)__popcll(m1 & below);
                uint32_t s2 = base + c01   + (uint32_t)__popcll(m2 & below);
                uint32_t s3 = base + c012  + (uint32_t)__popcll(m3 & below);
                if (p0 && s0 < CAP) sm.cand[p][s0] = k0;
                if (p1 && s1 < CAP) sm.cand[p][s1] = k1;
                if (p2 && s2 < CAP) sm.cand[p][s2] = k2;
                if (p3 && s3 < CAP) sm.cand[p][s3] = k3;
            }
        }
    }
    __syncthreads();                                        // B2
    const int cntv = (int)sm.ccnt[p];

    if (cntv <= CAP) {
        // both waves redundantly sentinel-fill the whole tail (identical
        // values -> benign race; avoids an extra barrier)
        for (int idx = cntv + lane; idx < CAP; idx += 64)
            sm.cand[p][idx] = 0xffffffffu;

        const int nb = (cntv + 15) >> 4;
        // rank-select: wave sub ranks idx = sub*64 + lane; wave 1 execz-skips
        // entirely when cntv <= 64 (common case) — lazy, measured faster than
        // the balanced interleave (R10 post-mortem).
        const int idx = sub*64 + lane;
        if (idx < cntv) {
            uint32_t km = sm.cand[p][idx];
            int rank = 0;
            for (int q = 0; q < nb; ++q) {
                const uint4* cp = (const uint4*)&sm.cand[p][q*16];
                uint4 u0 = cp[0];
                uint4 u1 = cp[1];
                uint4 u2 = cp[2];
                uint4 u3 = cp[3];
                rank += (u0.x < km) ? 1 : 0;
                rank += (u0.y < km) ? 1 : 0;
                rank += (u0.z < km) ? 1 : 0;
                rank += (u0.w < km) ? 1 : 0;
                rank += (u1.x < km) ? 1 : 0;
                rank += (u1.y < km) ? 1 : 0;
                rank += (u1.z < km) ? 1 : 0;
                rank += (u1.w < km) ? 1 : 0;
                rank += (u2.x < km) ? 1 : 0;
                rank += (u2.y < km) ? 1 : 0;
                rank += (u2.z < km) ? 1 : 0;
                rank += (u2.w < km) ? 1 : 0;
                rank += (u3.x < km) ? 1 : 0;
                rank += (u3.y < km) ? 1 : 0;
                rank += (u3.z < km) ? 1 : 0;
                rank += (u3.w < km) ? 1 : 0;
            }
            if (rank < KK) sm.recvs[p][rank] = (int)(km & 0xFFFFu);
        }
    } else if (sub == 0) {
        // cold fallback (~never): single wave of the pair, full recompute
        unsigned long long locmask = 0ull;
        if (selfLane)
            locmask |= 1ull << ((sgrp << 2) | selfc);
        for (int it = 0; it < KK; ++it) {
            unsigned long long best = ~0ull;
            for (int g = 0; g < 16; ++g) {
                float d[4];
                dist4s(p4, g, lane, px, py, pz, d);
                #pragma unroll
                for (int c = 0; c < 4; ++c) {
                    bool dead = ((locmask >> (g*4 + c)) & 1ull) != 0ull;
                    unsigned long long key = dead ? ~0ull
                        : ((((unsigned long long)__float_as_uint(d[c])) << 12)
                           | (unsigned)(g*256 + 4*lane + c));
                    best = best < key ? best : key;
                }
            }
            #pragma unroll
            for (int m = 32; m >= 1; m >>= 1) {
                unsigned long long o = __shfl_xor(best, m, 64);
                best = best < o ? best : o;
            }
            int j = (int)(best & 0xfffull);
            if (lane == 0) sm.recvs[p][it] = j;
            if (((j >> 2) & 63) == lane)
                locmask |= 1ull << ((j >> 8) * 4 + (j & 3));
        }
    }
    __syncthreads();                                        // B3

    // ---- phase D: gather own 16 edges (lane e<16 -> edge sub*16+e).
    //      rad stays in the gathering lane's REGISTER; phase E pulls it via
    //      __shfl (edge sub*16+L lives in lane L<16 of this wave) — the
    //      rads[] LDS write->read round trip is deleted. ----
    float cdx = 0.f, cdy = 0.f, cdz = 0.f, radD = 0.f;
    if (lane < 16) {
        int r = sm.recvs[p][sub*16 + lane];
        cdx = px - pos[3*r];
        cdy = py - pos[3*r+1];
        cdz = pz - pos[3*r+2];
        radD = __fadd_rn(__fadd_rn(__fmul_rn(cdx,cdx), __fmul_rn(cdy,cdy)),
                         __fmul_rn(cdz,cdz));
    }

    // ---- phase E: layer 1 for own 16 edges; lane = ch*4 + epr ----
    // own h1 rows [sub*16, sub*16+16) — written and later read by THIS wave
    // only (DS program order), so no barrier before MFMA.
    {
        const int ch = lane >> 2, epr = lane & 3;
        float4 wA = ((const float4*)W1)[ch*4    ];
        float4 wB = ((const float4*)W1)[ch*4 + 1];
        float4 wC = ((const float4*)W1)[ch*4 + 2];
        float4 wD = ((const float4*)W1)[ch*4 + 3];
        float4 bA = ((const float4*)b1)[ch*2], bB = ((const float4*)b1)[ch*2 + 1];
        float4 gA = ((const float4*)g1)[ch*2], gB = ((const float4*)g1)[ch*2 + 1];
        float av[8] = {wA.x, wA.z, wB.x, wB.z, wC.x, wC.z, wD.x, wD.z};
        float cv[8] = {ts*wA.y + bA.x, ts*wA.w + bA.y, ts*wB.y + bA.z, ts*wB.w + bA.w,
                       ts*wC.y + bB.x, ts*wC.w + bB.y, ts*wC.w*0.0f + ts*wD.y + bB.z, ts*wD.w + bB.w};
        // (no change in math: cv[6] = ts*wD.y + bB.z; the extra *0 term is
        //  removed below — keep exact original)
        cv[6] = ts*wD.y + bB.z;
        float gv[8] = {gA.x, gA.y, gA.z, gA.w, gB.x, gB.y, gB.z, gB.w};
        uint4* h1q = (uint4*)&sm.h1[p][0];
        #pragma unroll
        for (int g2i = 0; g2i < 4; ++g2i) {
            int E = sub*16 + 4*g2i + epr;         // own 16 edges
            float rad = __shfl(radD, 4*g2i + epr, 64);
            float sqv = rad*rad*A2 + 2.0f*rad*AC + C2;
            float rn  = fastrsq(sqv * (1.0f/HID) + 1e-5f);
            uint32_t pk[4];
            #pragma unroll
            for (int pp = 0; pp < 4; ++pp) {
                float va = siluf((rad*av[2*pp]   + cv[2*pp])   * rn * gv[2*pp]);
                float vb = siluf((rad*av[2*pp+1] + cv[2*pp+1]) * rn * gv[2*pp+1]);
                pk[pp] = pk2bf(va, vb);
            }
            h1q[E*16 + (ch ^ (E & 15))] = uint4{pk[0], pk[1], pk[2], pk[3]};
        }
    }

    // ---- epilogue constants (R9 position: loaded just before use) ----
    float g2v[8], w3v[8], b2v[8];
    #pragma unroll
    for (int nt = 0; nt < 8; ++nt) {
        int n = nt*16 + l15;
        g2v[nt] = g2[n]; w3v[nt] = W3[n]; b2v[nt] = b2[n];
    }

    // ---- phase F: layer 2 + epilogue, SINGLE m-tile (mt = sub) ----
    const bf16x8* h1v = (const bf16x8*)&sm.h1[p][0];
    {
        f32x4 acc[8];
        #pragma unroll
        for (int nt = 0; nt < 8; ++nt) acc[nt] = f32x4{0.f, 0.f, 0.f, 0.f};
        const int m = sub*16 + l15;
        if constexpr (WS) {
            const bf16x8* bv = (const bf16x8*)w2b;
            #pragma unroll
            for (int kk = 0; kk < 4; ++kk) {
                bf16x8 af = h1v[m*16 + ((kk*4 + lq) ^ l15)];
                #pragma unroll
                for (int nt = 0; nt < 8; ++nt)
                    acc[nt] = __builtin_amdgcn_mfma_f32_16x16x32_bf16(
                                  af, bv[(nt*4 + kk)*64 + lane], acc[nt], 0, 0, 0);
            }
        } else {
            const bf16x8* w2v = (const bf16x8*)sm.w2l;
            #pragma unroll
            for (int kk = 0; kk < 4; ++kk) {
                const int q = (kk*4 + lq) ^ l15;
                bf16x8 af = h1v[m*16 + q];
                #pragma unroll
                for (int nt = 0; nt < 8; ++nt)
                    acc[nt] = __builtin_amdgcn_mfma_f32_16x16x32_bf16(
                                  af, w2v[(nt*16 + l15)*16 + q], acc[nt], 0, 0, 0);
            }
        }

        float ss[4];
        #pragma unroll
        for (int r = 0; r < 4; ++r) {
            float t = 0.f;
            #pragma unroll
            for (int nt = 0; nt < 8; ++nt) {
                float zz = acc[nt][r] + b2v[nt];
                acc[nt][r] = zz;
                t += zz*zz;
            }
            ss[r] = rowsum16(t);
        }
        float sp[4];
        #pragma unroll
        for (int r = 0; r < 4; ++r) {
            float rn = fastrsq(ss[r] * (1.0f/HID) + 1e-5f);
            float t = 0.f;
            #pragma unroll
            for (int nt = 0; nt < 8; ++nt)
                t += siluf(acc[nt][r] * rn * g2v[nt]) * w3v[nt];
            sp[r] = rowsum16(t);
        }
        if (l15 == 0) {
            #pragma unroll
            for (int r = 0; r < 4; ++r)
                sm.sedge[p][sub*16 + lq*4 + r] = sp[r] + b3s;
        }
    }

    // ---- phase G: own 16 edge messages. Only lanes<16 contribute (rest 0)
    //      and only lane 0's value is consumed -> rowsum16 suffices (DPP,
    //      VALU pipe); the two shfl_xor cross-row steps are deleted. ----
    float mx = 0.f, my = 0.f, mz = 0.f;
    if (lane < 16) {
        float s = sm.sedge[p][sub*16 + lane];   // own half, own-wave writes
        mx = cdx * s; my = cdy * s; mz = cdz * s;
    }
    mx = rowsum16(mx);
    my = rowsum16(my);
    mz = rowsum16(mz);
    if (lane == 0) {
        sm.partial[p][sub][0] = mx;
        sm.partial[p][sub][1] = my;
        sm.partial[p][sub][2] = mz;
    }
    __syncthreads();                                        // B4
    if (sub == 0 && lane == 0) {
        float fx = sm.partial[p][0][0] + sm.partial[p][1][0];
        float fy = sm.partial[p][0][1] + sm.partial[p][1][1];
        float fz = sm.partial[p][0][2] + sm.partial[p][1][2];
        out[3*i    ] = px + fx * (1.0f/KK);
        out[3*i + 1] = py + fy * (1.0f/KK);
        out[3*i + 2] = pz + fz * (1.0f/KK);
    }
}

extern "C" void kernel_launch(void* const* d_in, const int* in_sizes, int n_in,
                              void* d_out, int out_size, void* d_ws, size_t ws_size,
                              hipStream_t stream) {
    (void)in_sizes; (void)n_in; (void)out_size;
    const float* pos = (const float*)d_in[0];
    const float* t   = (const float*)d_in[1];
    const float* W1  = (const float*)d_in[2];
    const float* b1  = (const float*)d_in[3];
    const float* g1  = (const float*)d_in[4];
    const float* W2  = (const float*)d_in[5];
    const float* b2  = (const float*)d_in[6];
    const float* g2  = (const float*)d_in[7];
    const float* W3  = (const float*)d_in[8];
    const float* b3  = (const float*)d_in[9];
    float* out = (float*)d_out;

    if (d_ws != nullptr && ws_size >= 32768) {
        prepack_w2<<<8, 256, 0, stream>>>(W2, (uint4*)d_ws);
        egnn_main<true><<<GRID, BLK, 0, stream>>>(
            pos, t, W1, b1, g1, W2, b2, g2, W3, b3, (const uint4*)d_ws, out);
    } else {
        egnn_main<false><<<GRID, BLK, 0, stream>>>(
            pos, t, W1, b1, g1, W2, b2, g2, W3, b3, nullptr, out);
    }
}

// Round 15
// 99.570 us; speedup vs baseline: 1.0744x; 1.0744x over previous
//
#include <hip/hip_runtime.h>
#include <stdint.h>

#define NN   4096
#define KK   32
#define HID  128
#define BLK  256
#define NPB  2                 // nodes per block
#define GRID (NN / NPB)        // 2048 blocks
#define CAP  128

typedef unsigned short bf16_t;
typedef __attribute__((ext_vector_type(8))) short bf16x8;
typedef __attribute__((ext_vector_type(4))) float f32x4;
typedef __attribute__((ext_vector_type(2))) float f32x2;

#define FINF __uint_as_float(0x7f800000u)

__device__ __forceinline__ uint32_t pk2bf(float lo, float hi) {
    uint32_t r;
    asm("v_cvt_pk_bf16_f32 %0, %1, %2" : "=v"(r) : "v"(lo), "v"(hi));
    return r;
}
__device__ __forceinline__ float fastrcp(float x) {
    float r; asm("v_rcp_f32 %0, %1" : "=v"(r) : "v"(x)); return r;
}
__device__ __forceinline__ float fastrsq(float x) {
    float r; asm("v_rsq_f32 %0, %1" : "=v"(r) : "v"(x)); return r;
}
__device__ __forceinline__ float siluf(float x) {
    return x * fastrcp(1.0f + __expf(-x));
}
__device__ __forceinline__ f32x2 pk_add(f32x2 a, f32x2 b) {
    f32x2 r; asm("v_pk_add_f32 %0, %1, %2" : "=v"(r) : "v"(a), "v"(b)); return r;
}
__device__ __forceinline__ f32x2 pk_sq(f32x2 a) {
    f32x2 r; asm("v_pk_mul_f32 %0, %1, %1" : "=v"(r) : "v"(a)); return r;
}

// DPP cross-lane sums (VALU pipe, no LDS)
template<int CTRL>
__device__ __forceinline__ float rsum_step(float x) {
    return x + __int_as_float(__builtin_amdgcn_update_dpp(
        0, __float_as_int(x), CTRL, 0xF, 0xF, true));
}
__device__ __forceinline__ float rowsum16(float x) {
    x = rsum_step<0xB1>(x);
    x = rsum_step<0x4E>(x);
    x = rsum_step<0x124>(x);
    x = rsum_step<0x128>(x);
    return x;
}
__device__ __forceinline__ float wsum64(float x) {
    x = rowsum16(x);
    x += __shfl_xor(x, 16, 64);
    x += __shfl_xor(x, 32, 64);
    return x;
}

// exact scalar distance (cold fallback only) — reference IEEE chain
__device__ __forceinline__ void dist4s(const float4* __restrict__ p4, int g, int lane,
                                       float px, float py, float pz, float d[4]) {
    float4 f0 = p4[g*192 + 3*lane];
    float4 f1 = p4[g*192 + 3*lane + 1];
    float4 f2 = p4[g*192 + 3*lane + 2];
    float jx[4] = {f0.x, f0.w, f1.z, f2.y};
    float jy[4] = {f0.y, f1.x, f1.w, f2.z};
    float jz[4] = {f0.z, f1.y, f2.x, f2.w};
    #pragma unroll
    for (int c = 0; c < 4; ++c) {
        float dx = px - jx[c], dy = py - jy[c], dz = pz - jz[c];
        d[c] = __fadd_rn(__fadd_rn(__fmul_rn(dx,dx), __fmul_rn(dy,dy)),
                         __fmul_rn(dz,dz));
    }
}

// ---- prepack: W2 fp32 -> bf16 in MFMA B-fragment order (frag f = NT*4+kk) ----
__global__ __launch_bounds__(256) void prepack_w2(
    const float* __restrict__ W2, uint4* __restrict__ w2b)
{
    int c  = blockIdx.x * 256 + threadIdx.x;
    int f  = c >> 6, ln = c & 63;
    int NT = f >> 2, kk = f & 3;
    int row = NT*16 + (ln & 15);
    int k0  = kk*32 + (ln >> 4) * 8;
    const float* s = W2 + row * HID + k0;
    float4 lo = *(const float4*)s;
    float4 hi = *(const float4*)(s + 4);
    uint4 pk;
    pk.x = pk2bf(lo.x, lo.y);
    pk.y = pk2bf(lo.z, lo.w);
    pk.z = pk2bf(hi.x, hi.y);
    pk.w = pk2bf(hi.z, hi.w);
    w2b[c] = pk;
}

template<bool WS>
struct __align__(16) Sm {
    ushort   h1[NPB][KK * HID];         // 16 KB: MFMA A-operand per node
    uint32_t cand[NPB][CAP];            // 1 KB
    uint32_t ccnt[NPB];                 // shared candidate counter per node
    ushort   smin[NPB][2][64];          // per-lane half-mins exchange
    float    rads[NPB][KK];
    float    sedge[NPB][KK];
    int      recvs[NPB][KK];
    float    partial[NPB][2][4];        // final message partials per wave
    uint32_t w2l[WS ? 4 : HID * 64];    // W2 staging only in no-workspace path
};

template<bool WS>
__global__ __launch_bounds__(BLK) void egnn_main(
    // TERMINAL CONFIG (measured best ~33us egnn; session 84 -> 33):
    //  - 2 nodes/block x 2 waves/node, 4 waves/SIMD, natural VGPR (~68).
    //  - NO min-waves bound: 8 waves/EU caps TOTAL regs at 64 incl. the 32-reg
    //    MFMA accumulator -> 32 arch VGPRs left -> catastrophic spills (R11).
    //  - NO hoisting epilogue constants to entry: +24 regs live across phases
    //    A-E starves phase-A scheduling (R12 +7us; confirmed by R13 revert).
    //  - KEEP per-candidate ds_add_rtn compaction: atomics from different
    //    lanes PIPELINE in the LDS queue; ballot-aggregated lane0-atomic +
    //    readfirstlane is a full-wave serialization point per group (R14 +8us).
    //  - KEEP rads[] in LDS and wsum64 phase-G (R14's shfl/rowsum16 variants
    //    regressed inside the same windows).
    //  - KEEP lazy rank-select (wave1 execz-skips): balanced interleave doubles
    //    work for no chain win (R10 +6us).
    const float* __restrict__ pos, const float* __restrict__ tptr,
    const float* __restrict__ W1,  const float* __restrict__ b1,
    const float* __restrict__ g1,  const float* __restrict__ W2,
    const float* __restrict__ b2,  const float* __restrict__ g2,
    const float* __restrict__ W3,  const float* __restrict__ b3,
    const uint4* __restrict__ w2b, float* __restrict__ out)
{
    __shared__ Sm<WS> sm;
    const int tid  = threadIdx.x;
    const int lane = tid & 63;
    const int wid  = tid >> 6;                  // 0..3
    const int p    = wid >> 1;                  // node slot in block (0..1)
    const int sub  = wid & 1;                   // half-wave of the pair
    const int i    = blockIdx.x * NPB + p;      // node handled by this pair
    const int l15  = lane & 15, lq = lane >> 4;

    if (tid < NPB) sm.ccnt[tid] = 0;            // visible after B1

    const float ts  = tptr[0];
    const float b3s = b3[0];

    // closed-form RMS coefficients (wave-reduced -> lane-uniform)
    float A2, AC, C2;
    {
        const float4 w1v = ((const float4*)W1)[lane];
        const float2 b1v = ((const float2*)b1)[lane];
        float t0 = ts * w1v.y + b1v.x;
        float t1 = ts * w1v.w + b1v.y;
        A2 = wsum64(w1v.x*w1v.x + w1v.z*w1v.z);
        AC = wsum64(w1v.x*t0    + w1v.z*t1);
        C2 = wsum64(t0*t0       + t1*t1);
    }

    if constexpr (!WS) {
        for (int idx = tid; idx < HID * 16; idx += BLK) {
            int row = idx >> 4, c = idx & 15;
            const float* src = W2 + row * HID + c * 8;
            float4 lo = *(const float4*)src;
            float4 hi = *(const float4*)(src + 4);
            uint4 pk;
            pk.x = pk2bf(lo.x, lo.y);
            pk.y = pk2bf(lo.z, lo.w);
            pk.z = pk2bf(hi.x, hi.y);
            pk.w = pk2bf(hi.z, hi.w);
            *((uint4*)&sm.w2l[row * 64 + 4 * (c ^ (row & 15))]) = pk;
        }
        // made visible by B1 below (before any w2l read)
    }

    const float px = pos[3*i], py = pos[3*i+1], pz = pos[3*i+2];
    const float4* p4 = (const float4*)pos;
    const f32x2 nPxy = {-px, -py}, nPzx = {-pz, -px}, nPyz = {-py, -pz};

    const int  sgrp     = i >> 8;
    const bool selfLane = ((i >> 2) & 63) == lane;
    const int  selfc    = i & 3;

    // ---- phase A: own-half distances (8 of 16 groups) into REGISTERS ----
    uint32_t dlo[8], dhi[8];
    float mind = FINF;
    #pragma unroll
    for (int gg = 0; gg < 8; ++gg) {
        const int g = sub*8 + gg;
        float4 f0 = p4[g*192 + 3*lane];   // x0 y0 z0 x1
        float4 f1 = p4[g*192 + 3*lane+1]; // y1 z1 x2 y2
        float4 f2 = p4[g*192 + 3*lane+2]; // z2 x3 y3 z3
        f32x2 S0 = pk_sq(pk_add(f32x2{f0.x, f0.y}, nPxy));
        f32x2 S1 = pk_sq(pk_add(f32x2{f0.z, f0.w}, nPzx));
        f32x2 S2 = pk_sq(pk_add(f32x2{f1.x, f1.y}, nPyz));
        f32x2 S3 = pk_sq(pk_add(f32x2{f1.z, f1.w}, nPxy));
        f32x2 S4 = pk_sq(pk_add(f32x2{f2.x, f2.y}, nPzx));
        f32x2 S5 = pk_sq(pk_add(f32x2{f2.z, f2.w}, nPyz));
        float d0 = S0.x + S0.y + S1.x;
        float d1 = S1.y + S2.x + S2.y;
        float d2 = S3.x + S3.y + S4.x;
        float d3 = S4.y + S5.x + S5.y;
        if (g == sgrp && selfLane) {
            d0 = (selfc == 0) ? FINF : d0;
            d1 = (selfc == 1) ? FINF : d1;
            d2 = (selfc == 2) ? FINF : d2;
            d3 = (selfc == 3) ? FINF : d3;
        }
        dlo[gg] = __builtin_amdgcn_perm(__float_as_uint(d1),
                                        __float_as_uint(d0), 0x07060302u);
        dhi[gg] = __builtin_amdgcn_perm(__float_as_uint(d3),
                                        __float_as_uint(d2), 0x07060302u);
        mind = fminf(fminf(fminf(mind, d0), fminf(d1, d2)), d3);
    }
    // exchange per-lane half-mins across the pair
    const uint32_t m16own = __float_as_uint(mind) >> 16;
    sm.smin[p][sub][lane] = (ushort)m16own;
    __syncthreads();                                        // B1
    uint32_t m16;
    {
        uint32_t o = (uint32_t)sm.smin[p][sub ^ 1][lane];
        m16 = m16own < o ? m16own : o;                      // full 64-j lane min
    }

    // ---- v = 32nd smallest combined sample-min (radix; duplicated per wave).
    //      Bit 15 skipped: distances >= 0 (self=+inf=0x7f80) => m16 < 0x8000
    //      for every lane => that iteration provably leaves v = 0. ----
    uint32_t v = 0;
    #pragma unroll
    for (int b = 14; b >= 0; --b) {
        uint32_t t = v | (1u << b);
        int nl = (int)__popcll(__ballot(m16 < t));
        if (nl < KK) v = t;
    }

    // ---- phase B: compaction straight from registers (own half) ----
    {
        const uint32_t vk = (v << 16) | 0xffffu;
        #pragma unroll
        for (int gg = 0; gg < 8; ++gg) {
            uint32_t jb = (uint32_t)((sub*8 + gg)*256 + 4*lane);
            uint32_t k0 = (dlo[gg] << 16) | jb;
            uint32_t k1 = (dlo[gg] & 0xffff0000u) | (jb + 1);
            uint32_t k2 = (dhi[gg] << 16) | (jb + 2);
            uint32_t k3 = (dhi[gg] & 0xffff0000u) | (jb + 3);
            if (k0 <= vk) { uint32_t s = atomicAdd(&sm.ccnt[p], 1u);
                            if (s < CAP) sm.cand[p][s] = k0; }
            if (k1 <= vk) { uint32_t s = atomicAdd(&sm.ccnt[p], 1u);
                            if (s < CAP) sm.cand[p][s] = k1; }
            if (k2 <= vk) { uint32_t s = atomicAdd(&sm.ccnt[p], 1u);
                            if (s < CAP) sm.cand[p][s] = k2; }
            if (k3 <= vk) { uint32_t s = atomicAdd(&sm.ccnt[p], 1u);
                            if (s < CAP) sm.cand[p][s] = k3; }
        }
    }
    __syncthreads();                                        // B2
    const int cntv = (int)sm.ccnt[p];

    if (cntv <= CAP) {
        // both waves redundantly sentinel-fill the whole tail (identical
        // values -> benign race; avoids an extra barrier)
        for (int idx = cntv + lane; idx < CAP; idx += 64)
            sm.cand[p][idx] = 0xffffffffu;

        const int nb = (cntv + 15) >> 4;
        // rank-select: wave sub ranks idx = sub*64 + lane; wave 1 execz-skips
        // entirely when cntv <= 64 (common case).
        const int idx = sub*64 + lane;
        if (idx < cntv) {
            uint32_t km = sm.cand[p][idx];
            int rank = 0;
            for (int q = 0; q < nb; ++q) {
                const uint4* cp = (const uint4*)&sm.cand[p][q*16];
                uint4 u0 = cp[0];
                uint4 u1 = cp[1];
                uint4 u2 = cp[2];
                uint4 u3 = cp[3];
                rank += (u0.x < km) ? 1 : 0;
                rank += (u0.y < km) ? 1 : 0;
                rank += (u0.z < km) ? 1 : 0;
                rank += (u0.w < km) ? 1 : 0;
                rank += (u1.x < km) ? 1 : 0;
                rank += (u1.y < km) ? 1 : 0;
                rank += (u1.z < km) ? 1 : 0;
                rank += (u1.w < km) ? 1 : 0;
                rank += (u2.x < km) ? 1 : 0;
                rank += (u2.y < km) ? 1 : 0;
                rank += (u2.z < km) ? 1 : 0;
                rank += (u2.w < km) ? 1 : 0;
                rank += (u3.x < km) ? 1 : 0;
                rank += (u3.y < km) ? 1 : 0;
                rank += (u3.z < km) ? 1 : 0;
                rank += (u3.w < km) ? 1 : 0;
            }
            if (rank < KK) sm.recvs[p][rank] = (int)(km & 0xFFFFu);
        }
    } else if (sub == 0) {
        // cold fallback (~never): single wave of the pair, full recompute
        unsigned long long locmask = 0ull;
        if (selfLane)
            locmask |= 1ull << ((sgrp << 2) | selfc);
        for (int it = 0; it < KK; ++it) {
            unsigned long long best = ~0ull;
            for (int g = 0; g < 16; ++g) {
                float d[4];
                dist4s(p4, g, lane, px, py, pz, d);
                #pragma unroll
                for (int c = 0; c < 4; ++c) {
                    bool dead = ((locmask >> (g*4 + c)) & 1ull) != 0ull;
                    unsigned long long key = dead ? ~0ull
                        : ((((unsigned long long)__float_as_uint(d[c])) << 12)
                           | (unsigned)(g*256 + 4*lane + c));
                    best = best < key ? best : key;
                }
            }
            #pragma unroll
            for (int m = 32; m >= 1; m >>= 1) {
                unsigned long long o = __shfl_xor(best, m, 64);
                best = best < o ? best : o;
            }
            int j = (int)(best & 0xfffull);
            if (lane == 0) sm.recvs[p][it] = j;
            if (((j >> 2) & 63) == lane)
                locmask |= 1ull << ((j >> 8) * 4 + (j & 3));
        }
    }
    __syncthreads();                                        // B3

    // ---- phase D: gather own 16 edges (lane e<16 -> edge sub*16+e) ----
    float cdx = 0.f, cdy = 0.f, cdz = 0.f;
    if (lane < 16) {
        int e = sub*16 + lane;
        int r = sm.recvs[p][e];
        cdx = px - pos[3*r];
        cdy = py - pos[3*r+1];
        cdz = pz - pos[3*r+2];
        float rad = __fadd_rn(__fadd_rn(__fmul_rn(cdx,cdx), __fmul_rn(cdy,cdy)),
                              __fmul_rn(cdz,cdz));
        sm.rads[p][e] = rad;
    }

    // ---- phase E: layer 1 for own 16 edges; lane = ch*4 + epr ----
    // own h1 rows [sub*16, sub*16+16) — written and later read by THIS wave
    // only (DS program order), so no barrier before MFMA.
    {
        const int ch = lane >> 2, epr = lane & 3;
        float4 wA = ((const float4*)W1)[ch*4    ];
        float4 wB = ((const float4*)W1)[ch*4 + 1];
        float4 wC = ((const float4*)W1)[ch*4 + 2];
        float4 wD = ((const float4*)W1)[ch*4 + 3];
        float4 bA = ((const float4*)b1)[ch*2], bB = ((const float4*)b1)[ch*2 + 1];
        float4 gA = ((const float4*)g1)[ch*2], gB = ((const float4*)g1)[ch*2 + 1];
        float av[8] = {wA.x, wA.z, wB.x, wB.z, wC.x, wC.z, wD.x, wD.z};
        float cv[8] = {ts*wA.y + bA.x, ts*wA.w + bA.y, ts*wB.y + bA.z, ts*wB.w + bA.w,
                       ts*wC.y + bB.x, ts*wC.w + bB.y, ts*wD.y + bB.z, ts*wD.w + bB.w};
        float gv[8] = {gA.x, gA.y, gA.z, gA.w, gB.x, gB.y, gB.z, gB.w};
        uint4* h1q = (uint4*)&sm.h1[p][0];
        #pragma unroll
        for (int g2i = 0; g2i < 4; ++g2i) {
            int E = sub*16 + 4*g2i + epr;         // own 16 edges
            float rad = sm.rads[p][E];
            float sqv = rad*rad*A2 + 2.0f*rad*AC + C2;
            float rn  = fastrsq(sqv * (1.0f/HID) + 1e-5f);
            uint32_t pk[4];
            #pragma unroll
            for (int pp = 0; pp < 4; ++pp) {
                float va = siluf((rad*av[2*pp]   + cv[2*pp])   * rn * gv[2*pp]);
                float vb = siluf((rad*av[2*pp+1] + cv[2*pp+1]) * rn * gv[2*pp+1]);
                pk[pp] = pk2bf(va, vb);
            }
            h1q[E*16 + (ch ^ (E & 15))] = uint4{pk[0], pk[1], pk[2], pk[3]};
        }
    }

    // ---- epilogue constants (loaded just before use; do NOT hoist) ----
    float g2v[8], w3v[8], b2v[8];
    #pragma unroll
    for (int nt = 0; nt < 8; ++nt) {
        int n = nt*16 + l15;
        g2v[nt] = g2[n]; w3v[nt] = W3[n]; b2v[nt] = b2[n];
    }

    // ---- phase F: layer 2 + epilogue, SINGLE m-tile (mt = sub) ----
    const bf16x8* h1v = (const bf16x8*)&sm.h1[p][0];
    {
        f32x4 acc[8];
        #pragma unroll
        for (int nt = 0; nt < 8; ++nt) acc[nt] = f32x4{0.f, 0.f, 0.f, 0.f};
        const int m = sub*16 + l15;
        if constexpr (WS) {
            const bf16x8* bv = (const bf16x8*)w2b;
            #pragma unroll
            for (int kk = 0; kk < 4; ++kk) {
                bf16x8 af = h1v[m*16 + ((kk*4 + lq) ^ l15)];
                #pragma unroll
                for (int nt = 0; nt < 8; ++nt)
                    acc[nt] = __builtin_amdgcn_mfma_f32_16x16x32_bf16(
                                  af, bv[(nt*4 + kk)*64 + lane], acc[nt], 0, 0, 0);
            }
        } else {
            const bf16x8* w2v = (const bf16x8*)sm.w2l;
            #pragma unroll
            for (int kk = 0; kk < 4; ++kk) {
                const int q = (kk*4 + lq) ^ l15;
                bf16x8 af = h1v[m*16 + q];
                #pragma unroll
                for (int nt = 0; nt < 8; ++nt)
                    acc[nt] = __builtin_amdgcn_mfma_f32_16x16x32_bf16(
                                  af, w2v[(nt*16 + l15)*16 + q], acc[nt], 0, 0, 0);
            }
        }

        float ss[4];
        #pragma unroll
        for (int r = 0; r < 4; ++r) {
            float t = 0.f;
            #pragma unroll
            for (int nt = 0; nt < 8; ++nt) {
                float zz = acc[nt][r] + b2v[nt];
                acc[nt][r] = zz;
                t += zz*zz;
            }
            ss[r] = rowsum16(t);
        }
        float sp[4];
        #pragma unroll
        for (int r = 0; r < 4; ++r) {
            float rn = fastrsq(ss[r] * (1.0f/HID) + 1e-5f);
            float t = 0.f;
            #pragma unroll
            for (int nt = 0; nt < 8; ++nt)
                t += siluf(acc[nt][r] * rn * g2v[nt]) * w3v[nt];
            sp[r] = rowsum16(t);
        }
        if (l15 == 0) {
            #pragma unroll
            for (int r = 0; r < 4; ++r)
                sm.sedge[p][sub*16 + lq*4 + r] = sp[r] + b3s;
        }
    }

    // ---- phase G: own 16 edge messages, then pair combine ----
    float mx = 0.f, my = 0.f, mz = 0.f;
    if (lane < 16) {
        float s = sm.sedge[p][sub*16 + lane];   // own half, own-wave writes
        mx = cdx * s; my = cdy * s; mz = cdz * s;
    }
    mx = wsum64(mx);
    my = wsum64(my);
    mz = wsum64(mz);
    if (lane == 0) {
        sm.partial[p][sub][0] = mx;
        sm.partial[p][sub][1] = my;
        sm.partial[p][sub][2] = mz;
    }
    __syncthreads();                                        // B4
    if (sub == 0 && lane == 0) {
        float fx = sm.partial[p][0][0] + sm.partial[p][1][0];
        float fy = sm.partial[p][0][1] + sm.partial[p][1][1];
        float fz = sm.partial[p][0][2] + sm.partial[p][1][2];
        out[3*i    ] = px + fx * (1.0f/KK);
        out[3*i + 1] = py + fy * (1.0f/KK);
        out[3*i + 2] = pz + fz * (1.0f/KK);
    }
}

extern "C" void kernel_launch(void* const* d_in, const int* in_sizes, int n_in,
                              void* d_out, int out_size, void* d_ws, size_t ws_size,
                              hipStream_t stream) {
    (void)in_sizes; (void)n_in; (void)out_size;
    const float* pos = (const float*)d_in[0];
    const float* t   = (const float*)d_in[1];
    const float* W1  = (const float*)d_in[2];
    const float* b1  = (const float*)d_in[3];
    const float* g1  = (const float*)d_in[4];
    const float* W2  = (const float*)d_in[5];
    const float* b2  = (const float*)d_in[6];
    const float* g2  = (const float*)d_in[7];
    const float* W3  = (const float*)d_in[8];
    const float* b3  = (const float*)d_in[9];
    float* out = (float*)d_out;

    if (d_ws != nullptr && ws_size >= 32768) {
        prepack_w2<<<8, 256, 0, stream>>>(W2, (uint4*)d_ws);
        egnn_main<true><<<GRID, BLK, 0, stream>>>(
            pos, t, W1, b1, g1, W2, b2, g2, W3, b3, (const uint4*)d_ws, out);
    } else {
        egnn_main<false><<<GRID, BLK, 0, stream>>>(
            pos, t, W1, b1, g1, W2, b2, g2, W3, b3, nullptr, out);
    }
}